// Round 14
// baseline (479.817 us; speedup 1.0000x reference)
//
#include <hip/hip_runtime.h>
#include <hip/hip_fp16.h>

#define N_NODES 100000
#define N_EDGES 1600000

typedef float f4nt __attribute__((ext_vector_type(4)));

__device__ __forceinline__ int ntload_i(const int* p) { return __builtin_nontemporal_load(p); }
__device__ __forceinline__ float ntload_f(const float* p) { return __builtin_nontemporal_load(p); }
__device__ __forceinline__ float4 ntload_f4(const float4* p) {
    f4nt v = __builtin_nontemporal_load((const f4nt*)p);
    return make_float4(v.x, v.y, v.z, v.w);
}
__device__ __forceinline__ void ntstore_f4(float4* p, float4 v) {
    f4nt t; t.x = v.x; t.y = v.y; t.z = v.z; t.w = v.w;
    __builtin_nontemporal_store(t, (f4nt*)p);
}

// ---------------- degree (XCD-partitioned, nt streaming reads) ---------------
__global__ __launch_bounds__(256) void degree_kernel(const int* __restrict__ dst,
                                                     int* __restrict__ cnt, int E) {
    const int range = blockIdx.x & 7;
    const int lo = range * (N_NODES / 8);
    const int hi = lo + (N_NODES / 8);
    int i = (blockIdx.x >> 3) * blockDim.x + threadIdx.x;
    const int stride = (gridDim.x >> 3) * blockDim.x;
    for (; i < E; i += stride) {
        const int d = ntload_i(&dst[i]);
        if (d >= lo && d < hi) atomicAdd(&cnt[d], 1);
    }
}

// ---------------- hierarchical exclusive scan (cnt -> cursor), inv fused -----
__global__ __launch_bounds__(256) void block_sum_kernel(const int* __restrict__ cnt,
                                                        int* __restrict__ bsum, int N) {
    __shared__ int s[256];
    const int tid = threadIdx.x;
    const int i = blockIdx.x * 256 + tid;
    s[tid] = (i < N) ? cnt[i] : 0;
    __syncthreads();
#pragma unroll
    for (int d = 128; d > 0; d >>= 1) {
        if (tid < d) s[tid] += s[tid + d];
        __syncthreads();
    }
    if (tid == 0) bsum[blockIdx.x] = s[0];
}

__global__ __launch_bounds__(512) void scan_bsum_kernel(int* __restrict__ bsum, int NB) {
    __shared__ int s[512];
    const int tid = threadIdx.x;
    const int v = (tid < NB) ? bsum[tid] : 0;
    s[tid] = v;
    __syncthreads();
    for (int d = 1; d < 512; d <<= 1) {
        const int t = (tid >= d) ? s[tid - d] : 0;
        __syncthreads();
        s[tid] += t;
        __syncthreads();
    }
    if (tid < NB) bsum[tid] = s[tid] - v;  // exclusive
}

__global__ __launch_bounds__(256) void make_cursor_kernel(const int* __restrict__ cnt,
                                                          const int* __restrict__ bsum,
                                                          int* __restrict__ cursor,
                                                          float* __restrict__ inv, int N) {
    __shared__ int s[256];
    const int tid = threadIdx.x;
    const int i = blockIdx.x * 256 + tid;
    const int v = (i < N) ? cnt[i] : 0;
    s[tid] = v;
    __syncthreads();
    for (int d = 1; d < 256; d <<= 1) {
        const int t = (tid >= d) ? s[tid - d] : 0;
        __syncthreads();
        s[tid] += t;
        __syncthreads();
    }
    if (i < N) {
        cursor[i] = bsum[blockIdx.x] + s[tid] - v;
        inv[i] = (v > 0) ? (1.0f / (float)v) : 0.0f;
    }
}

// ---------------- XCD-partitioned CSR scatter, nt streaming reads ------------
// spf stripe per XCD = 3.2MB; nt on dst/src/ea keeps those streams from
// evicting the spf lines, so 16B payload writes merge to full 64B sectors.
__global__ __launch_bounds__(256) void scatter_pack_kernel(
    const int* __restrict__ src, const int* __restrict__ dst,
    const float* __restrict__ ea,
    int* __restrict__ cursor, float4* __restrict__ spf, int E) {
    const int range = blockIdx.x & 7;
    const int lo = range * (N_NODES / 8);
    const int hi = lo + (N_NODES / 8);
    int i = (blockIdx.x >> 3) * blockDim.x + threadIdx.x;
    const int stride = (gridDim.x >> 3) * blockDim.x;
    for (; i < E; i += stride) {
        const int d = ntload_i(&dst[i]);
        if (d >= lo && d < hi) {
            const int pos = atomicAdd(&cursor[d], 1);
            spf[pos] = make_float4(__int_as_float(ntload_i(&src[i])),
                                   ntload_f(&ea[3 * (size_t)i + 0]),
                                   ntload_f(&ea[3 * (size_t)i + 1]),
                                   ntload_f(&ea[3 * (size_t)i + 2]));
        }
    }
}

// ---------------- node GEMM: P1(half) = x @ W1a[0:6] + b1a ----------------
__global__ __launch_bounds__(256) void node_gemm6h(
    const float* __restrict__ x, const float* __restrict__ W,
    const float* __restrict__ bias, __half* __restrict__ out_, int N) {
    int n = blockIdx.x * blockDim.x + threadIdx.x;
    if (n >= N) return;
    const float* row = x + (size_t)n * 6;
    float v[6];
#pragma unroll
    for (int k = 0; k < 6; ++k) v[k] = ntload_f(&row[k]);
    __half2* orow = (__half2*)(out_ + (size_t)n * 64);
    for (int g = 0; g < 16; ++g) {
        float a0 = bias[4 * g + 0], a1 = bias[4 * g + 1];
        float a2 = bias[4 * g + 2], a3 = bias[4 * g + 3];
#pragma unroll
        for (int k = 0; k < 6; ++k) {
            const float m = v[k];
            const float* w = &W[k * 64 + 4 * g];
            a0 = fmaf(m, w[0], a0);
            a1 = fmaf(m, w[1], a1);
            a2 = fmaf(m, w[2], a2);
            a3 = fmaf(m, w[3], a3);
        }
        orow[2 * g]     = __floats2half2_rn(a0, a1);
        orow[2 * g + 1] = __floats2half2_rn(a2, a3);
    }
}

// ---------------- PURE aggregate, DIN=64 fp16, 8-lane-subgroup gather --------
// nt on the spf stream + nt output store keep the 12.8MB P table L2-resident.
__global__ __launch_bounds__(256) void agg64_pure(
    const __half* __restrict__ P,    // [N,64] half
    const float4* __restrict__ spf,  // [E] CSR-ordered (src, ea0, ea1, ea2)
    const int* __restrict__ cursor, const int* __restrict__ cnt,
    const float* __restrict__ inv,
    const float* __restrict__ We,    // [3,64]
    __half* __restrict__ A, int N) {
    const int lane  = threadIdx.x & 63;
    const int sub   = lane >> 3;   // 0..7 subgroup = edge slot
    const int p     = lane & 7;    // 0..7 column block (8 cols)
    const int gw    = (blockIdx.x * blockDim.x + threadIdx.x) >> 6;
    const int nwave = (gridDim.x * blockDim.x) >> 6;

    float we0[8], we1[8], we2[8];
#pragma unroll
    for (int k = 0; k < 8; ++k) {
        we0[k] = We[0 * 64 + 8 * p + k];
        we1[k] = We[1 * 64 + 8 * p + k];
        we2[k] = We[2 * 64 + 8 * p + k];
    }

    for (int n = gw; n < N; n += nwave) {
        const int end   = cursor[n];
        const int count = cnt[n];
        int j = end - count;
        const float s_inv = inv[n];

        float s0 = 0.f, s1 = 0.f, s2 = 0.f, s3 = 0.f;
        float s4 = 0.f, s5 = 0.f, s6 = 0.f, s7 = 0.f;

#define GRP8(base, valid)                                                        \
    {                                                                            \
        const int ei = (base) + sub;                                             \
        const float4 f = ntload_f4(&spf[ei < end ? ei : end - 1]);               \
        const float4 rawf = *(const float4*)((const __half*)P +                  \
                            ((size_t)__float_as_int(f.x) << 6) + 8 * p);         \
        const __half2* hp = (const __half2*)&rawf;                               \
        const float2 q0 = __half22float2(hp[0]);                                 \
        const float2 q1 = __half22float2(hp[1]);                                 \
        const float2 q2 = __half22float2(hp[2]);                                 \
        const float2 q3 = __half22float2(hp[3]);                                 \
        const float h0 = fmaxf(fmaf(f.w, we2[0], fmaf(f.z, we1[0], fmaf(f.y, we0[0], q0.x))), 0.f); \
        const float h1 = fmaxf(fmaf(f.w, we2[1], fmaf(f.z, we1[1], fmaf(f.y, we0[1], q0.y))), 0.f); \
        const float h2 = fmaxf(fmaf(f.w, we2[2], fmaf(f.z, we1[2], fmaf(f.y, we0[2], q1.x))), 0.f); \
        const float h3 = fmaxf(fmaf(f.w, we2[3], fmaf(f.z, we1[3], fmaf(f.y, we0[3], q1.y))), 0.f); \
        const float h4 = fmaxf(fmaf(f.w, we2[4], fmaf(f.z, we1[4], fmaf(f.y, we0[4], q2.x))), 0.f); \
        const float h5 = fmaxf(fmaf(f.w, we2[5], fmaf(f.z, we1[5], fmaf(f.y, we0[5], q2.y))), 0.f); \
        const float h6 = fmaxf(fmaf(f.w, we2[6], fmaf(f.z, we1[6], fmaf(f.y, we0[6], q3.x))), 0.f); \
        const float h7 = fmaxf(fmaf(f.w, we2[7], fmaf(f.z, we1[7], fmaf(f.y, we0[7], q3.y))), 0.f); \
        if (valid) {                                                             \
            s0 += h0; s1 += h1; s2 += h2; s3 += h3;                              \
            s4 += h4; s5 += h5; s6 += h6; s7 += h7;                              \
        }                                                                        \
    }

        for (; j + 16 <= end; j += 16) { GRP8(j, true) GRP8(j + 8, true) }
        if (j + 8 <= end) { GRP8(j, true) j += 8; }
        {
            const int rem = end - j;
            if (rem > 0) { GRP8(j, (sub < rem)) }
        }
#undef GRP8

#define RED(d) \
        s0 += __shfl_xor(s0, d); s1 += __shfl_xor(s1, d); \
        s2 += __shfl_xor(s2, d); s3 += __shfl_xor(s3, d); \
        s4 += __shfl_xor(s4, d); s5 += __shfl_xor(s5, d); \
        s6 += __shfl_xor(s6, d); s7 += __shfl_xor(s7, d);
        RED(8) RED(16) RED(32)
#undef RED

        if (lane < 8) {
            __half2 h01 = __floats2half2_rn(s0 * s_inv, s1 * s_inv);
            __half2 h23 = __floats2half2_rn(s2 * s_inv, s3 * s_inv);
            __half2 h45 = __floats2half2_rn(s4 * s_inv, s5 * s_inv);
            __half2 h67 = __floats2half2_rn(s6 * s_inv, s7 * s_inv);
            union { __half2 h[4]; float4 f; } u;
            u.h[0] = h01; u.h[1] = h23; u.h[2] = h45; u.h[3] = h67;
            ntstore_f4((float4*)(A + (size_t)n * 64 + 8 * p), u.f);
        }
    }
}

// ---------------- PURE aggregate, DIN=32 fp16, 4-lane-subgroup gather --------
__global__ __launch_bounds__(256) void agg32_pure(
    const __half* __restrict__ P,    // [N,32] half
    const float4* __restrict__ spf,
    const int* __restrict__ cursor, const int* __restrict__ cnt,
    const float* __restrict__ inv,
    const float* __restrict__ We,    // [3,32]
    __half* __restrict__ A, int N) {
    const int lane  = threadIdx.x & 63;
    const int sub   = lane >> 2;   // 0..15 subgroup = edge slot
    const int p     = lane & 3;    // 0..3 column block (8 cols)
    const int gw    = (blockIdx.x * blockDim.x + threadIdx.x) >> 6;
    const int nwave = (gridDim.x * blockDim.x) >> 6;

    float we0[8], we1[8], we2[8];
#pragma unroll
    for (int k = 0; k < 8; ++k) {
        we0[k] = We[0 * 32 + 8 * p + k];
        we1[k] = We[1 * 32 + 8 * p + k];
        we2[k] = We[2 * 32 + 8 * p + k];
    }

    for (int n = gw; n < N; n += nwave) {
        const int end   = cursor[n];
        const int count = cnt[n];
        int j = end - count;
        const float s_inv = inv[n];

        float s0 = 0.f, s1 = 0.f, s2 = 0.f, s3 = 0.f;
        float s4 = 0.f, s5 = 0.f, s6 = 0.f, s7 = 0.f;

#define GRP16(base, valid)                                                       \
    {                                                                            \
        const int ei = (base) + sub;                                             \
        const float4 f = ntload_f4(&spf[ei < end ? ei : end - 1]);               \
        const float4 rawf = *(const float4*)((const __half*)P +                  \
                            ((size_t)__float_as_int(f.x) << 5) + 8 * p);         \
        const __half2* hp = (const __half2*)&rawf;                               \
        const float2 q0 = __half22float2(hp[0]);                                 \
        const float2 q1 = __half22float2(hp[1]);                                 \
        const float2 q2 = __half22float2(hp[2]);                                 \
        const float2 q3 = __half22float2(hp[3]);                                 \
        const float h0 = fmaxf(fmaf(f.w, we2[0], fmaf(f.z, we1[0], fmaf(f.y, we0[0], q0.x))), 0.f); \
        const float h1 = fmaxf(fmaf(f.w, we2[1], fmaf(f.z, we1[1], fmaf(f.y, we0[1], q0.y))), 0.f); \
        const float h2 = fmaxf(fmaf(f.w, we2[2], fmaf(f.z, we1[2], fmaf(f.y, we0[2], q1.x))), 0.f); \
        const float h3 = fmaxf(fmaf(f.w, we2[3], fmaf(f.z, we1[3], fmaf(f.y, we0[3], q1.y))), 0.f); \
        const float h4 = fmaxf(fmaf(f.w, we2[4], fmaf(f.z, we1[4], fmaf(f.y, we0[4], q2.x))), 0.f); \
        const float h5 = fmaxf(fmaf(f.w, we2[5], fmaf(f.z, we1[5], fmaf(f.y, we0[5], q2.y))), 0.f); \
        const float h6 = fmaxf(fmaf(f.w, we2[6], fmaf(f.z, we1[6], fmaf(f.y, we0[6], q3.x))), 0.f); \
        const float h7 = fmaxf(fmaf(f.w, we2[7], fmaf(f.z, we1[7], fmaf(f.y, we0[7], q3.y))), 0.f); \
        if (valid) {                                                             \
            s0 += h0; s1 += h1; s2 += h2; s3 += h3;                              \
            s4 += h4; s5 += h5; s6 += h6; s7 += h7;                              \
        }                                                                        \
    }

        for (; j + 16 <= end; j += 16) { GRP16(j, true) }
        {
            const int rem = end - j;
            if (rem > 0) { GRP16(j, (sub < rem)) }
        }
#undef GRP16

#define RED(d) \
        s0 += __shfl_xor(s0, d); s1 += __shfl_xor(s1, d); \
        s2 += __shfl_xor(s2, d); s3 += __shfl_xor(s3, d); \
        s4 += __shfl_xor(s4, d); s5 += __shfl_xor(s5, d); \
        s6 += __shfl_xor(s6, d); s7 += __shfl_xor(s7, d);
        RED(4) RED(8) RED(16) RED(32)
#undef RED

        if (lane < 4) {
            __half2 h01 = __floats2half2_rn(s0 * s_inv, s1 * s_inv);
            __half2 h23 = __floats2half2_rn(s2 * s_inv, s3 * s_inv);
            __half2 h45 = __floats2half2_rn(s4 * s_inv, s5 * s_inv);
            __half2 h67 = __floats2half2_rn(s6 * s_inv, s7 * s_inv);
            union { __half2 h[4]; float4 f; } u;
            u.h[0] = h01; u.h[1] = h23; u.h[2] = h45; u.h[3] = h67;
            ntstore_f4((float4*)(A + (size_t)n * 32 + 8 * p), u.f);
        }
    }
}

// ---------------- fused double MLP: thread-per-node, s_load weights ----------
template <int OUT2>
__global__ __launch_bounds__(256) void node_mlp2(
    const __half* __restrict__ in_,
    const float* __restrict__ W1, const float* __restrict__ b1,
    const float* __restrict__ W2, const float* __restrict__ b2,
    const float* __restrict__ inv,
    __half* __restrict__ out_, int N) {
    int n = blockIdx.x * blockDim.x + threadIdx.x;
    if (n >= N) return;
    const __half* row = in_ + (size_t)n * 64;
    float v[64];
#pragma unroll
    for (int q = 0; q < 8; ++q) {
        float4 raw = ntload_f4(&((const float4*)row)[q]);
        const __half2* hp = (const __half2*)&raw;
#pragma unroll
        for (int t = 0; t < 4; ++t) {
            const float2 f2 = __half22float2(hp[t]);
            v[8 * q + 2 * t]     = f2.x;
            v[8 * q + 2 * t + 1] = f2.y;
        }
    }
    const float bs = (inv[n] != 0.0f) ? 1.0f : 0.0f;

    __half2 mh[32];
    for (int g = 0; g < 16; ++g) {
        float a0 = b1[4 * g + 0] * bs, a1 = b1[4 * g + 1] * bs;
        float a2 = b1[4 * g + 2] * bs, a3 = b1[4 * g + 3] * bs;
#pragma unroll
        for (int k = 0; k < 64; ++k) {
            const float m = v[k];
            const float* w = &W1[k * 64 + 4 * g];
            a0 = fmaf(m, w[0], a0);
            a1 = fmaf(m, w[1], a1);
            a2 = fmaf(m, w[2], a2);
            a3 = fmaf(m, w[3], a3);
        }
        a0 = fmaxf(a0, 0.f); a1 = fmaxf(a1, 0.f);
        a2 = fmaxf(a2, 0.f); a3 = fmaxf(a3, 0.f);
        mh[2 * g]     = __floats2half2_rn(a0, a1);
        mh[2 * g + 1] = __floats2half2_rn(a2, a3);
    }
#pragma unroll
    for (int t = 0; t < 32; ++t) {
        const float2 f2 = __half22float2(mh[t]);
        v[2 * t]     = f2.x;
        v[2 * t + 1] = f2.y;
    }
    __half2 hout[OUT2 / 2];
    for (int g = 0; g < OUT2 / 4; ++g) {
        float a0 = b2[4 * g + 0], a1 = b2[4 * g + 1];
        float a2 = b2[4 * g + 2], a3 = b2[4 * g + 3];
#pragma unroll
        for (int k = 0; k < 64; ++k) {
            const float m = v[k];
            const float* w = &W2[k * OUT2 + 4 * g];
            a0 = fmaf(m, w[0], a0);
            a1 = fmaf(m, w[1], a1);
            a2 = fmaf(m, w[2], a2);
            a3 = fmaf(m, w[3], a3);
        }
        hout[2 * g]     = __floats2half2_rn(a0, a1);
        hout[2 * g + 1] = __floats2half2_rn(a2, a3);
    }
    float4* orow = (float4*)(out_ + (size_t)n * OUT2);
#pragma unroll
    for (int q = 0; q < OUT2 / 8; ++q) orow[q] = ((const float4*)hout)[q];
}

// final: fp16 in -> fp32 out, masked bias, no relu
__global__ __launch_bounds__(256) void node_mlp_final(
    const __half* __restrict__ in_, const float* __restrict__ W,
    const float* __restrict__ bias, const float* __restrict__ inv,
    float* __restrict__ out_, int N) {
    int n = blockIdx.x * blockDim.x + threadIdx.x;
    if (n >= N) return;
    const __half* row = in_ + (size_t)n * 32;
    float v[32];
#pragma unroll
    for (int q = 0; q < 4; ++q) {
        float4 raw = ntload_f4(&((const float4*)row)[q]);
        const __half2* hp = (const __half2*)&raw;
#pragma unroll
        for (int t = 0; t < 4; ++t) {
            const float2 f2 = __half22float2(hp[t]);
            v[8 * q + 2 * t]     = f2.x;
            v[8 * q + 2 * t + 1] = f2.y;
        }
    }
    const float bs = (inv[n] != 0.0f) ? 1.0f : 0.0f;
    float* orow = out_ + (size_t)n * 32;
    for (int g = 0; g < 8; ++g) {
        float a0 = bias[4 * g + 0] * bs, a1 = bias[4 * g + 1] * bs;
        float a2 = bias[4 * g + 2] * bs, a3 = bias[4 * g + 3] * bs;
#pragma unroll
        for (int k = 0; k < 32; ++k) {
            const float m = v[k];
            const float* w = &W[k * 32 + 4 * g];
            a0 = fmaf(m, w[0], a0);
            a1 = fmaf(m, w[1], a1);
            a2 = fmaf(m, w[2], a2);
            a3 = fmaf(m, w[3], a3);
        }
        ((float4*)orow)[g] = make_float4(a0, a1, a2, a3);
    }
}

extern "C" void kernel_launch(void* const* d_in, const int* in_sizes, int n_in,
                              void* d_out, int out_size, void* d_ws, size_t ws_size,
                              hipStream_t stream) {
    const float* x   = (const float*)d_in[0];
    const int*   ei  = (const int*)d_in[1];
    const float* ea  = (const float*)d_in[2];
    const float* W1a = (const float*)d_in[3];
    const float* b1a = (const float*)d_in[4];
    const float* W1b = (const float*)d_in[5];
    const float* b1b = (const float*)d_in[6];
    const float* W2a = (const float*)d_in[7];
    const float* b2a = (const float*)d_in[8];
    const float* W2b = (const float*)d_in[9];
    const float* b2b = (const float*)d_in[10];
    const float* W3a = (const float*)d_in[11];
    const float* b3a = (const float*)d_in[12];
    const float* W3b = (const float*)d_in[13];
    const float* b3b = (const float*)d_in[14];

    const int* src = ei;
    const int* dst = ei + N_EDGES;
    float* out = (float*)d_out;

    // workspace (byte offsets), total ~66 MB:
    // cnt 0x0 | inv 0x80000 | bsum 0x100000 | cursor 0x110000 |
    // spf(float4) 0x200000 (25.6MB) | b0 0x1B00000 (12.8MB half [N,64]) |
    // b1 0x2800000 (12.8MB)
    char* ws = (char*)d_ws;
    int*    cnt    = (int*)(ws);
    float*  inv    = (float*)(ws + 0x80000);
    int*    bsum   = (int*)(ws + 0x100000);
    int*    cursor = (int*)(ws + 0x110000);
    float4* spf    = (float4*)(ws + 0x200000);
    __half* b0     = (__half*)(ws + 0x1B00000);
    __half* b1     = (__half*)(ws + 0x2800000);

    const int NBLK = (N_NODES + 255) / 256;  // 391
    const int ABLK = 1024;                   // 4096 waves for pure aggs

    // graph preprocessing (shared by all 3 layers)
    hipMemsetAsync(cnt, 0, N_NODES * sizeof(int), stream);
    degree_kernel<<<2048, 256, 0, stream>>>(dst, cnt, N_EDGES);
    block_sum_kernel<<<NBLK, 256, 0, stream>>>(cnt, bsum, N_NODES);
    scan_bsum_kernel<<<1, 512, 0, stream>>>(bsum, NBLK);
    make_cursor_kernel<<<NBLK, 256, 0, stream>>>(cnt, bsum, cursor, inv, N_NODES);
    scatter_pack_kernel<<<2048, 256, 0, stream>>>(src, dst, ea, cursor, spf, N_EDGES);
    // cursor[n] = end offset of node n's CSR range

    // P1 = half(x @ W1a[0:6] + b1a) -> b0
    node_gemm6h<<<NBLK, 256, 0, stream>>>(x, W1a, b1a, b0, N_NODES);

    // ---- layer 1 ----
    agg64_pure<<<ABLK, 256, 0, stream>>>(b0, spf, cursor, cnt, inv, W1a + 6 * 64, b1, N_NODES);
    node_mlp2<64><<<NBLK, 256, 0, stream>>>(b1, W1b, b1b, W2a, b2a, inv, b0, N_NODES);

    // ---- layer 2 ----
    agg64_pure<<<ABLK, 256, 0, stream>>>(b0, spf, cursor, cnt, inv, W2a + 64 * 64, b1, N_NODES);
    node_mlp2<32><<<NBLK, 256, 0, stream>>>(b1, W2b, b2b, W3a, b3a, inv, b0, N_NODES);

    // ---- layer 3 ----
    agg32_pure<<<ABLK, 256, 0, stream>>>(b0, spf, cursor, cnt, inv, W3a + 64 * 32, b1, N_NODES);
    node_mlp_final<<<NBLK, 256, 0, stream>>>(b1, W3b, b3b, inv, out, N_NODES);
}

// Round 15
// 441.766 us; speedup vs baseline: 1.0861x; 1.0861x over previous
//
#include <hip/hip_runtime.h>
#include <hip/hip_fp16.h>

#define N_NODES 100000
#define N_EDGES 1600000

// ---------------- degree: plain grid-stride (dst read ONCE, 6.4MB) ----------
__global__ __launch_bounds__(256) void degree_kernel(const int* __restrict__ dst,
                                                     int* __restrict__ cnt, int E) {
    int i = blockIdx.x * blockDim.x + threadIdx.x;
    const int stride = gridDim.x * blockDim.x;
    for (; i < E; i += stride) atomicAdd(&cnt[dst[i]], 1);
}

// ---------------- hierarchical exclusive scan (cnt -> cursor), inv fused -----
__global__ __launch_bounds__(256) void block_sum_kernel(const int* __restrict__ cnt,
                                                        int* __restrict__ bsum, int N) {
    __shared__ int s[256];
    const int tid = threadIdx.x;
    const int i = blockIdx.x * 256 + tid;
    s[tid] = (i < N) ? cnt[i] : 0;
    __syncthreads();
#pragma unroll
    for (int d = 128; d > 0; d >>= 1) {
        if (tid < d) s[tid] += s[tid + d];
        __syncthreads();
    }
    if (tid == 0) bsum[blockIdx.x] = s[0];
}

__global__ __launch_bounds__(512) void scan_bsum_kernel(int* __restrict__ bsum, int NB) {
    __shared__ int s[512];
    const int tid = threadIdx.x;
    const int v = (tid < NB) ? bsum[tid] : 0;
    s[tid] = v;
    __syncthreads();
    for (int d = 1; d < 512; d <<= 1) {
        const int t = (tid >= d) ? s[tid - d] : 0;
        __syncthreads();
        s[tid] += t;
        __syncthreads();
    }
    if (tid < NB) bsum[tid] = s[tid] - v;  // exclusive
}

__global__ __launch_bounds__(256) void make_cursor_kernel(const int* __restrict__ cnt,
                                                          const int* __restrict__ bsum,
                                                          int* __restrict__ cursor,
                                                          float* __restrict__ inv, int N) {
    __shared__ int s[256];
    const int tid = threadIdx.x;
    const int i = blockIdx.x * 256 + tid;
    const int v = (i < N) ? cnt[i] : 0;
    s[tid] = v;
    __syncthreads();
    for (int d = 1; d < 256; d <<= 1) {
        const int t = (tid >= d) ? s[tid - d] : 0;
        __syncthreads();
        s[tid] += t;
        __syncthreads();
    }
    if (i < N) {
        cursor[i] = bsum[blockIdx.x] + s[tid] - v;
        inv[i] = (v > 0) ? (1.0f / (float)v) : 0.0f;
    }
}

// ---------------- XCD-partitioned CSR scatter, float4 payload ----------------
__global__ __launch_bounds__(256) void scatter_pack_kernel(
    const int* __restrict__ src, const int* __restrict__ dst,
    const float* __restrict__ ea,
    int* __restrict__ cursor, float4* __restrict__ spf, int E) {
    const int range = blockIdx.x & 7;
    const int lo = range * (N_NODES / 8);
    const int hi = lo + (N_NODES / 8);
    int i = (blockIdx.x >> 3) * blockDim.x + threadIdx.x;
    const int stride = (gridDim.x >> 3) * blockDim.x;
    for (; i < E; i += stride) {
        const int d = dst[i];
        if (d >= lo && d < hi) {
            const int pos = atomicAdd(&cursor[d], 1);
            spf[pos] = make_float4(__int_as_float(src[i]),
                                   ea[3 * (size_t)i + 0],
                                   ea[3 * (size_t)i + 1],
                                   ea[3 * (size_t)i + 2]);
        }
    }
}

// ---------------- node GEMM: P1(half) = x @ W1a[0:6] + b1a ----------------
__global__ __launch_bounds__(256) void node_gemm6h(
    const float* __restrict__ x, const float* __restrict__ W,
    const float* __restrict__ bias, __half* __restrict__ out_, int N) {
    int n = blockIdx.x * blockDim.x + threadIdx.x;
    if (n >= N) return;
    const float* row = x + (size_t)n * 6;
    float v[6];
#pragma unroll
    for (int k = 0; k < 6; ++k) v[k] = row[k];
    __half2* orow = (__half2*)(out_ + (size_t)n * 64);
    for (int g = 0; g < 16; ++g) {
        float a0 = bias[4 * g + 0], a1 = bias[4 * g + 1];
        float a2 = bias[4 * g + 2], a3 = bias[4 * g + 3];
#pragma unroll
        for (int k = 0; k < 6; ++k) {
            const float m = v[k];
            const float* w = &W[k * 64 + 4 * g];
            a0 = fmaf(m, w[0], a0);
            a1 = fmaf(m, w[1], a1);
            a2 = fmaf(m, w[2], a2);
            a3 = fmaf(m, w[3], a3);
        }
        orow[2 * g]     = __floats2half2_rn(a0, a1);
        orow[2 * g + 1] = __floats2half2_rn(a2, a3);
    }
}

// ---------------- PURE aggregate, DIN=64 fp16, 8-lane-subgroup gather --------
__global__ __launch_bounds__(256) void agg64_pure(
    const __half* __restrict__ P,    // [N,64] half
    const float4* __restrict__ spf,  // [E] CSR-ordered (src, ea0, ea1, ea2)
    const int* __restrict__ cursor, const int* __restrict__ cnt,
    const float* __restrict__ inv,
    const float* __restrict__ We,    // [3,64]
    __half* __restrict__ A, int N) {
    const int lane  = threadIdx.x & 63;
    const int sub   = lane >> 3;   // 0..7 subgroup = edge slot
    const int p     = lane & 7;    // 0..7 column block (8 cols)
    const int gw    = (blockIdx.x * blockDim.x + threadIdx.x) >> 6;
    const int nwave = (gridDim.x * blockDim.x) >> 6;

    float we0[8], we1[8], we2[8];
#pragma unroll
    for (int k = 0; k < 8; ++k) {
        we0[k] = We[0 * 64 + 8 * p + k];
        we1[k] = We[1 * 64 + 8 * p + k];
        we2[k] = We[2 * 64 + 8 * p + k];
    }

    for (int n = gw; n < N; n += nwave) {
        const int end   = cursor[n];
        const int count = cnt[n];
        int j = end - count;
        const float s_inv = inv[n];

        float s0 = 0.f, s1 = 0.f, s2 = 0.f, s3 = 0.f;
        float s4 = 0.f, s5 = 0.f, s6 = 0.f, s7 = 0.f;

#define GRP8(base, valid)                                                        \
    {                                                                            \
        const int ei = (base) + sub;                                             \
        const float4 f = spf[ei < end ? ei : end - 1];                           \
        const float4 rawf = *(const float4*)((const __half*)P +                  \
                            ((size_t)__float_as_int(f.x) << 6) + 8 * p);         \
        const __half2* hp = (const __half2*)&rawf;                               \
        const float2 q0 = __half22float2(hp[0]);                                 \
        const float2 q1 = __half22float2(hp[1]);                                 \
        const float2 q2 = __half22float2(hp[2]);                                 \
        const float2 q3 = __half22float2(hp[3]);                                 \
        const float h0 = fmaxf(fmaf(f.w, we2[0], fmaf(f.z, we1[0], fmaf(f.y, we0[0], q0.x))), 0.f); \
        const float h1 = fmaxf(fmaf(f.w, we2[1], fmaf(f.z, we1[1], fmaf(f.y, we0[1], q0.y))), 0.f); \
        const float h2 = fmaxf(fmaf(f.w, we2[2], fmaf(f.z, we1[2], fmaf(f.y, we0[2], q1.x))), 0.f); \
        const float h3 = fmaxf(fmaf(f.w, we2[3], fmaf(f.z, we1[3], fmaf(f.y, we0[3], q1.y))), 0.f); \
        const float h4 = fmaxf(fmaf(f.w, we2[4], fmaf(f.z, we1[4], fmaf(f.y, we0[4], q2.x))), 0.f); \
        const float h5 = fmaxf(fmaf(f.w, we2[5], fmaf(f.z, we1[5], fmaf(f.y, we0[5], q2.y))), 0.f); \
        const float h6 = fmaxf(fmaf(f.w, we2[6], fmaf(f.z, we1[6], fmaf(f.y, we0[6], q3.x))), 0.f); \
        const float h7 = fmaxf(fmaf(f.w, we2[7], fmaf(f.z, we1[7], fmaf(f.y, we0[7], q3.y))), 0.f); \
        if (valid) {                                                             \
            s0 += h0; s1 += h1; s2 += h2; s3 += h3;                              \
            s4 += h4; s5 += h5; s6 += h6; s7 += h7;                              \
        }                                                                        \
    }

        for (; j + 16 <= end; j += 16) { GRP8(j, true) GRP8(j + 8, true) }
        if (j + 8 <= end) { GRP8(j, true) j += 8; }
        {
            const int rem = end - j;
            if (rem > 0) { GRP8(j, (sub < rem)) }
        }
#undef GRP8

#define RED(d) \
        s0 += __shfl_xor(s0, d); s1 += __shfl_xor(s1, d); \
        s2 += __shfl_xor(s2, d); s3 += __shfl_xor(s3, d); \
        s4 += __shfl_xor(s4, d); s5 += __shfl_xor(s5, d); \
        s6 += __shfl_xor(s6, d); s7 += __shfl_xor(s7, d);
        RED(8) RED(16) RED(32)
#undef RED

        if (lane < 8) {
            __half2 h01 = __floats2half2_rn(s0 * s_inv, s1 * s_inv);
            __half2 h23 = __floats2half2_rn(s2 * s_inv, s3 * s_inv);
            __half2 h45 = __floats2half2_rn(s4 * s_inv, s5 * s_inv);
            __half2 h67 = __floats2half2_rn(s6 * s_inv, s7 * s_inv);
            union { __half2 h[4]; float4 f; } u;
            u.h[0] = h01; u.h[1] = h23; u.h[2] = h45; u.h[3] = h67;
            *(float4*)(A + (size_t)n * 64 + 8 * p) = u.f;
        }
    }
}

// ---------------- PURE aggregate, DIN=32 fp16, 4-lane-subgroup gather --------
__global__ __launch_bounds__(256) void agg32_pure(
    const __half* __restrict__ P,    // [N,32] half
    const float4* __restrict__ spf,
    const int* __restrict__ cursor, const int* __restrict__ cnt,
    const float* __restrict__ inv,
    const float* __restrict__ We,    // [3,32]
    __half* __restrict__ A, int N) {
    const int lane  = threadIdx.x & 63;
    const int sub   = lane >> 2;   // 0..15 subgroup = edge slot
    const int p     = lane & 3;    // 0..3 column block (8 cols)
    const int gw    = (blockIdx.x * blockDim.x + threadIdx.x) >> 6;
    const int nwave = (gridDim.x * blockDim.x) >> 6;

    float we0[8], we1[8], we2[8];
#pragma unroll
    for (int k = 0; k < 8; ++k) {
        we0[k] = We[0 * 32 + 8 * p + k];
        we1[k] = We[1 * 32 + 8 * p + k];
        we2[k] = We[2 * 32 + 8 * p + k];
    }

    for (int n = gw; n < N; n += nwave) {
        const int end   = cursor[n];
        const int count = cnt[n];
        int j = end - count;
        const float s_inv = inv[n];

        float s0 = 0.f, s1 = 0.f, s2 = 0.f, s3 = 0.f;
        float s4 = 0.f, s5 = 0.f, s6 = 0.f, s7 = 0.f;

#define GRP16(base, valid)                                                       \
    {                                                                            \
        const int ei = (base) + sub;                                             \
        const float4 f = spf[ei < end ? ei : end - 1];                           \
        const float4 rawf = *(const float4*)((const __half*)P +                  \
                            ((size_t)__float_as_int(f.x) << 5) + 8 * p);         \
        const __half2* hp = (const __half2*)&rawf;                               \
        const float2 q0 = __half22float2(hp[0]);                                 \
        const float2 q1 = __half22float2(hp[1]);                                 \
        const float2 q2 = __half22float2(hp[2]);                                 \
        const float2 q3 = __half22float2(hp[3]);                                 \
        const float h0 = fmaxf(fmaf(f.w, we2[0], fmaf(f.z, we1[0], fmaf(f.y, we0[0], q0.x))), 0.f); \
        const float h1 = fmaxf(fmaf(f.w, we2[1], fmaf(f.z, we1[1], fmaf(f.y, we0[1], q0.y))), 0.f); \
        const float h2 = fmaxf(fmaf(f.w, we2[2], fmaf(f.z, we1[2], fmaf(f.y, we0[2], q1.x))), 0.f); \
        const float h3 = fmaxf(fmaf(f.w, we2[3], fmaf(f.z, we1[3], fmaf(f.y, we0[3], q1.y))), 0.f); \
        const float h4 = fmaxf(fmaf(f.w, we2[4], fmaf(f.z, we1[4], fmaf(f.y, we0[4], q2.x))), 0.f); \
        const float h5 = fmaxf(fmaf(f.w, we2[5], fmaf(f.z, we1[5], fmaf(f.y, we0[5], q2.y))), 0.f); \
        const float h6 = fmaxf(fmaf(f.w, we2[6], fmaf(f.z, we1[6], fmaf(f.y, we0[6], q3.x))), 0.f); \
        const float h7 = fmaxf(fmaf(f.w, we2[7], fmaf(f.z, we1[7], fmaf(f.y, we0[7], q3.y))), 0.f); \
        if (valid) {                                                             \
            s0 += h0; s1 += h1; s2 += h2; s3 += h3;                              \
            s4 += h4; s5 += h5; s6 += h6; s7 += h7;                              \
        }                                                                        \
    }

        for (; j + 16 <= end; j += 16) { GRP16(j, true) }
        {
            const int rem = end - j;
            if (rem > 0) { GRP16(j, (sub < rem)) }
        }
#undef GRP16

#define RED(d) \
        s0 += __shfl_xor(s0, d); s1 += __shfl_xor(s1, d); \
        s2 += __shfl_xor(s2, d); s3 += __shfl_xor(s3, d); \
        s4 += __shfl_xor(s4, d); s5 += __shfl_xor(s5, d); \
        s6 += __shfl_xor(s6, d); s7 += __shfl_xor(s7, d);
        RED(4) RED(8) RED(16) RED(32)
#undef RED

        if (lane < 4) {
            __half2 h01 = __floats2half2_rn(s0 * s_inv, s1 * s_inv);
            __half2 h23 = __floats2half2_rn(s2 * s_inv, s3 * s_inv);
            __half2 h45 = __floats2half2_rn(s4 * s_inv, s5 * s_inv);
            __half2 h67 = __floats2half2_rn(s6 * s_inv, s7 * s_inv);
            union { __half2 h[4]; float4 f; } u;
            u.h[0] = h01; u.h[1] = h23; u.h[2] = h45; u.h[3] = h67;
            *(float4*)(A + (size_t)n * 32 + 8 * p) = u.f;
        }
    }
}

// ---------------- fused double MLP: thread-per-node, s_load weights ----------
template <int OUT2>
__global__ __launch_bounds__(256) void node_mlp2(
    const __half* __restrict__ in_,
    const float* __restrict__ W1, const float* __restrict__ b1,
    const float* __restrict__ W2, const float* __restrict__ b2,
    const float* __restrict__ inv,
    __half* __restrict__ out_, int N) {
    int n = blockIdx.x * blockDim.x + threadIdx.x;
    if (n >= N) return;
    const __half* row = in_ + (size_t)n * 64;
    float v[64];
#pragma unroll
    for (int q = 0; q < 8; ++q) {
        float4 raw = ((const float4*)row)[q];
        const __half2* hp = (const __half2*)&raw;
#pragma unroll
        for (int t = 0; t < 4; ++t) {
            const float2 f2 = __half22float2(hp[t]);
            v[8 * q + 2 * t]     = f2.x;
            v[8 * q + 2 * t + 1] = f2.y;
        }
    }
    const float bs = (inv[n] != 0.0f) ? 1.0f : 0.0f;

    __half2 mh[32];
    for (int g = 0; g < 16; ++g) {
        float a0 = b1[4 * g + 0] * bs, a1 = b1[4 * g + 1] * bs;
        float a2 = b1[4 * g + 2] * bs, a3 = b1[4 * g + 3] * bs;
#pragma unroll
        for (int k = 0; k < 64; ++k) {
            const float m = v[k];
            const float* w = &W1[k * 64 + 4 * g];
            a0 = fmaf(m, w[0], a0);
            a1 = fmaf(m, w[1], a1);
            a2 = fmaf(m, w[2], a2);
            a3 = fmaf(m, w[3], a3);
        }
        a0 = fmaxf(a0, 0.f); a1 = fmaxf(a1, 0.f);
        a2 = fmaxf(a2, 0.f); a3 = fmaxf(a3, 0.f);
        mh[2 * g]     = __floats2half2_rn(a0, a1);
        mh[2 * g + 1] = __floats2half2_rn(a2, a3);
    }
#pragma unroll
    for (int t = 0; t < 32; ++t) {
        const float2 f2 = __half22float2(mh[t]);
        v[2 * t]     = f2.x;
        v[2 * t + 1] = f2.y;
    }
    __half2 hout[OUT2 / 2];
    for (int g = 0; g < OUT2 / 4; ++g) {
        float a0 = b2[4 * g + 0], a1 = b2[4 * g + 1];
        float a2 = b2[4 * g + 2], a3 = b2[4 * g + 3];
#pragma unroll
        for (int k = 0; k < 64; ++k) {
            const float m = v[k];
            const float* w = &W2[k * OUT2 + 4 * g];
            a0 = fmaf(m, w[0], a0);
            a1 = fmaf(m, w[1], a1);
            a2 = fmaf(m, w[2], a2);
            a3 = fmaf(m, w[3], a3);
        }
        hout[2 * g]     = __floats2half2_rn(a0, a1);
        hout[2 * g + 1] = __floats2half2_rn(a2, a3);
    }
    float4* orow = (float4*)(out_ + (size_t)n * OUT2);
#pragma unroll
    for (int q = 0; q < OUT2 / 8; ++q) orow[q] = ((const float4*)hout)[q];
}

// final: fp16 in -> fp32 out, masked bias, no relu
__global__ __launch_bounds__(256) void node_mlp_final(
    const __half* __restrict__ in_, const float* __restrict__ W,
    const float* __restrict__ bias, const float* __restrict__ inv,
    float* __restrict__ out_, int N) {
    int n = blockIdx.x * blockDim.x + threadIdx.x;
    if (n >= N) return;
    const __half* row = in_ + (size_t)n * 32;
    float v[32];
#pragma unroll
    for (int q = 0; q < 4; ++q) {
        float4 raw = ((const float4*)row)[q];
        const __half2* hp = (const __half2*)&raw;
#pragma unroll
        for (int t = 0; t < 4; ++t) {
            const float2 f2 = __half22float2(hp[t]);
            v[8 * q + 2 * t]     = f2.x;
            v[8 * q + 2 * t + 1] = f2.y;
        }
    }
    const float bs = (inv[n] != 0.0f) ? 1.0f : 0.0f;
    float* orow = out_ + (size_t)n * 32;
    for (int g = 0; g < 8; ++g) {
        float a0 = bias[4 * g + 0] * bs, a1 = bias[4 * g + 1] * bs;
        float a2 = bias[4 * g + 2] * bs, a3 = bias[4 * g + 3] * bs;
#pragma unroll
        for (int k = 0; k < 32; ++k) {
            const float m = v[k];
            const float* w = &W[k * 32 + 4 * g];
            a0 = fmaf(m, w[0], a0);
            a1 = fmaf(m, w[1], a1);
            a2 = fmaf(m, w[2], a2);
            a3 = fmaf(m, w[3], a3);
        }
        ((float4*)orow)[g] = make_float4(a0, a1, a2, a3);
    }
}

extern "C" void kernel_launch(void* const* d_in, const int* in_sizes, int n_in,
                              void* d_out, int out_size, void* d_ws, size_t ws_size,
                              hipStream_t stream) {
    const float* x   = (const float*)d_in[0];
    const int*   ei  = (const int*)d_in[1];
    const float* ea  = (const float*)d_in[2];
    const float* W1a = (const float*)d_in[3];
    const float* b1a = (const float*)d_in[4];
    const float* W1b = (const float*)d_in[5];
    const float* b1b = (const float*)d_in[6];
    const float* W2a = (const float*)d_in[7];
    const float* b2a = (const float*)d_in[8];
    const float* W2b = (const float*)d_in[9];
    const float* b2b = (const float*)d_in[10];
    const float* W3a = (const float*)d_in[11];
    const float* b3a = (const float*)d_in[12];
    const float* W3b = (const float*)d_in[13];
    const float* b3b = (const float*)d_in[14];

    const int* src = ei;
    const int* dst = ei + N_EDGES;
    float* out = (float*)d_out;

    // workspace (byte offsets), total ~66 MB:
    // cnt 0x0 | inv 0x80000 | bsum 0x100000 | cursor 0x110000 |
    // spf(float4) 0x200000 (25.6MB) | b0 0x1B00000 (12.8MB half [N,64]) |
    // b1 0x2800000 (12.8MB)
    char* ws = (char*)d_ws;
    int*    cnt    = (int*)(ws);
    float*  inv    = (float*)(ws + 0x80000);
    int*    bsum   = (int*)(ws + 0x100000);
    int*    cursor = (int*)(ws + 0x110000);
    float4* spf    = (float4*)(ws + 0x200000);
    __half* b0     = (__half*)(ws + 0x1B00000);
    __half* b1     = (__half*)(ws + 0x2800000);

    const int NBLK = (N_NODES + 255) / 256;  // 391
    const int ABLK = 1024;                   // 4096 waves for pure aggs

    // graph preprocessing (shared by all 3 layers)
    hipMemsetAsync(cnt, 0, N_NODES * sizeof(int), stream);
    degree_kernel<<<2048, 256, 0, stream>>>(dst, cnt, N_EDGES);
    block_sum_kernel<<<NBLK, 256, 0, stream>>>(cnt, bsum, N_NODES);
    scan_bsum_kernel<<<1, 512, 0, stream>>>(bsum, NBLK);
    make_cursor_kernel<<<NBLK, 256, 0, stream>>>(cnt, bsum, cursor, inv, N_NODES);
    scatter_pack_kernel<<<2048, 256, 0, stream>>>(src, dst, ea, cursor, spf, N_EDGES);
    // cursor[n] = end offset of node n's CSR range

    // P1 = half(x @ W1a[0:6] + b1a) -> b0
    node_gemm6h<<<NBLK, 256, 0, stream>>>(x, W1a, b1a, b0, N_NODES);

    // ---- layer 1 ----
    agg64_pure<<<ABLK, 256, 0, stream>>>(b0, spf, cursor, cnt, inv, W1a + 6 * 64, b1, N_NODES);
    node_mlp2<64><<<NBLK, 256, 0, stream>>>(b1, W1b, b1b, W2a, b2a, inv, b0, N_NODES);

    // ---- layer 2 ----
    agg64_pure<<<ABLK, 256, 0, stream>>>(b0, spf, cursor, cnt, inv, W2a + 64 * 64, b1, N_NODES);
    node_mlp2<32><<<NBLK, 256, 0, stream>>>(b1, W2b, b2b, W3a, b3a, inv, b0, N_NODES);

    // ---- layer 3 ----
    agg32_pure<<<ABLK, 256, 0, stream>>>(b0, spf, cursor, cnt, inv, W3a + 64 * 32, b1, N_NODES);
    node_mlp_final<<<NBLK, 256, 0, stream>>>(b1, W3b, b3b, inv, out, N_NODES);
}